// Round 7
// baseline (216.123 us; speedup 1.0000x reference)
//
#include <hip/hip_runtime.h>
#include <hip/hip_bf16.h>

#define Mpts 50000
#define Npts 50000
#define Hn 32
#define Cc 128
#define Kk 15
#define NCW 240   // K*CPG = 15*16

typedef __attribute__((ext_vector_type(8))) short short8;
typedef __attribute__((ext_vector_type(4))) float f32x4;
typedef __attribute__((ext_vector_type(2))) float f32x2;

__device__ inline ushort f2bf(float f) {
  __hip_bfloat16 h = __float2bfloat16(f);
  return *reinterpret_cast<ushort*>(&h);
}

// ================= K0: transpose W1,W2 -> bf16 [n][k]; zero pad row & stats ==
__global__ __launch_bounds__(256) void k0_weights(
    const float* __restrict__ W1, const float* __restrict__ W2,
    ushort* __restrict__ W1t, ushort* __restrict__ W2t,
    ushort* __restrict__ sfb, float* __restrict__ stats)
{
  __shared__ ushort TT[240][66];
  const int t = threadIdx.x;
  const int b = blockIdx.x;
  if (b < 2) {                       // W1: 64 k-rows x 128 n-cols
    const int k0 = b * 64;
#pragma unroll
    for (int i = 0; i < 32; ++i) {
      int e = t + i * 256;           // coalesced
      int r = e >> 7, c = e & 127;
      TT[c][r] = f2bf(W1[(size_t)(k0 + r) * Cc + c]);
    }
    __syncthreads();
    int n = t >> 1, half = t & 1;
    union { short8 v[4]; ushort u[32]; } pk;
#pragma unroll
    for (int i = 0; i < 32; ++i) pk.u[i] = TT[n][half * 32 + i];
#pragma unroll
    for (int q = 0; q < 4; ++q)
      *(short8*)(W1t + (size_t)n * Cc + k0 + half * 32 + q * 8) = pk.v[q];
  } else if (b < 4) {                // W2: 64 k-rows x 240 n-cols
    const int k0 = (b - 2) * 64;
    for (int i = 0; i < 60; ++i) {
      int e = t + i * 256;           // coalesced
      int r = e / 240, c = e % 240;
      TT[c][r] = f2bf(W2[(size_t)(k0 + r) * NCW + c]);
    }
    __syncthreads();
    if (t < 240) {
      union { short8 v[8]; ushort u[64]; } pk;
#pragma unroll
      for (int i = 0; i < 64; ++i) pk.u[i] = TT[t][i];
#pragma unroll
      for (int q = 0; q < 8; ++q)
        *(short8*)(W2t + (size_t)t * Cc + k0 + q * 8) = pk.v[q];
    }
  } else {
    if (t < 16) {
      short8 z = short8{0,0,0,0,0,0,0,0};
      *(short8*)(sfb + (size_t)Npts * Cc + t * 8) = z;
    }
    if (t < 128) {
      float4 z4 = make_float4(0.f, 0.f, 0.f, 0.f);
      *(float4*)(stats + t * 4) = z4;
    }
  }
}

// ================= K1: fused MLP, column-split waves (BM=64) =================
// wave w: stage1 cols [32w,32w+32) of ALL 64 rows; stage2 j in [4w, 4w+NJ)
__global__ __launch_bounds__(256, 3) void k1_mlp(
    const float* __restrict__ sfeat, const ushort* __restrict__ W1t,
    const float* __restrict__ b1, const ushort* __restrict__ W2t,
    const float* __restrict__ b2, ushort* __restrict__ sfb,
    ushort* __restrict__ cw, float* __restrict__ stats)
{
  __shared__ __align__(16) ushort shT[64 * 128];   // A tile, later h tile

  const int t = threadIdx.x;
  const int r0 = blockIdx.x * 64;
  const int wid = t >> 6, lane = t & 63;
  const int l16 = lane & 15, lq = lane >> 4;

  // ---- stage A: batch-issue loads, then cvt + write LDS/global ----
  float4 fA[4], fB[4];
#pragma unroll
  for (int p = 0; p < 4; ++p) {
    int id = p * 256 + t;            // chunk id: row = id/16, chunk = id%16
    int r = id >> 4, c = id & 15;
    int g = r0 + r;
    fA[p] = make_float4(0.f, 0.f, 0.f, 0.f);
    fB[p] = make_float4(0.f, 0.f, 0.f, 0.f);
    if (g < Mpts) {
      const float* src = sfeat + (size_t)g * Cc + c * 8;
      fA[p] = *(const float4*)(src);
      fB[p] = *(const float4*)(src + 4);
    }
  }
#pragma unroll
  for (int p = 0; p < 4; ++p) {
    int id = p * 256 + t;
    int r = id >> 4, c = id & 15;
    int g = r0 + r;
    union { short8 s; ushort u[8]; } pk;
    pk.u[0] = f2bf(fA[p].x); pk.u[1] = f2bf(fA[p].y); pk.u[2] = f2bf(fA[p].z); pk.u[3] = f2bf(fA[p].w);
    pk.u[4] = f2bf(fB[p].x); pk.u[5] = f2bf(fB[p].y); pk.u[6] = f2bf(fB[p].z); pk.u[7] = f2bf(fB[p].w);
    if (g < Mpts) *(short8*)(sfb + (size_t)g * Cc + c * 8) = pk.s;
    int byte = ((r * 256) + c * 16) ^ ((r & 7) << 4);
    *(short8*)((char*)shT + byte) = pk.s;
  }
  __syncthreads();

  const int axor = (l16 & 7) << 4;   // rt*16 doesn't change row&7

  // ---- stage 1: cols [wid*32, wid*32+32) x 64 rows ----
  const int nt0 = wid * 2;
  f32x4 acc1[2][4];                  // [nt][rt]
#pragma unroll
  for (int n = 0; n < 2; ++n)
#pragma unroll
    for (int rt = 0; rt < 4; ++rt) acc1[n][rt] = f32x4{0.f, 0.f, 0.f, 0.f};
#pragma unroll
  for (int kt = 0; kt < 4; ++kt) {
    const int koff = kt * 32 + lq * 8;
    short8 b0 = *(const short8*)(W1t + (size_t)((nt0 + 0) * 16 + l16) * Cc + koff);
    short8 b1v = *(const short8*)(W1t + (size_t)((nt0 + 1) * 16 + l16) * Cc + koff);
#pragma unroll
    for (int rt = 0; rt < 4; ++rt) {
      int row = rt * 16 + l16;
      short8 a = *(const short8*)((const char*)shT + ((row * 256 + koff * 2) ^ axor));
      acc1[0][rt] = __builtin_amdgcn_mfma_f32_16x16x32_bf16(a, b0,  acc1[0][rt], 0, 0, 0);
      acc1[1][rt] = __builtin_amdgcn_mfma_f32_16x16x32_bf16(a, b1v, acc1[1][rt], 0, 0, 0);
    }
  }
  __syncthreads();   // everyone done reading A-tile
  // bias + LeakyReLU -> shT cols [wid*32, wid*32+32), all 64 rows
#pragma unroll
  for (int n = 0; n < 2; ++n) {
    int col = (nt0 + n) * 16 + l16;
    float bias = b1[col];
#pragma unroll
    for (int rt = 0; rt < 4; ++rt)
#pragma unroll
      for (int reg = 0; reg < 4; ++reg) {
        float h = acc1[n][rt][reg] + bias;
        h = h >= 0.f ? h : 0.1f * h;
        int row = rt * 16 + lq * 4 + reg;
        int byte = ((row * 256) + col * 2) ^ ((row & 7) << 4);
        *(ushort*)((char*)shT + byte) = f2bf(h);
      }
  }
  __syncthreads();   // h complete (cross-wave)

  // ---- stage 2: j in [wid*4, wid*4+NJ) x 64 rows ----
  const int j0 = wid * 4;
  const int NJ = (wid == 3) ? 3 : 4;
  f32x4 acc2[4][4];                  // [j][rt]
#pragma unroll
  for (int j = 0; j < 4; ++j)
#pragma unroll
    for (int rt = 0; rt < 4; ++rt) acc2[j][rt] = f32x4{0.f, 0.f, 0.f, 0.f};
#pragma unroll
  for (int kt = 0; kt < 4; ++kt) {
    const int koff = kt * 32 + lq * 8;
    short8 bj[4];
    for (int j = 0; j < NJ; ++j)
      bj[j] = *(const short8*)(W2t + (size_t)((j0 + j) * 16 + l16) * Cc + koff);
#pragma unroll
    for (int rt = 0; rt < 4; ++rt) {
      int row = rt * 16 + l16;
      short8 a = *(const short8*)((const char*)shT + ((row * 256 + koff * 2) ^ axor));
      for (int j = 0; j < NJ; ++j)
        acc2[j][rt] = __builtin_amdgcn_mfma_f32_16x16x32_bf16(a, bj[j], acc2[j][rt], 0, 0, 0);
    }
  }

  // ---- cw write + per-j stats (each j owned by exactly one wave) ----
  float s[4], ss[4];
#pragma unroll
  for (int j = 0; j < 4; ++j) { s[j] = 0.f; ss[j] = 0.f; }
  for (int j = 0; j < NJ; ++j) {
    int col = (j0 + j) * 16 + l16;
    float bias = b2[col];
#pragma unroll
    for (int rt = 0; rt < 4; ++rt)
#pragma unroll
      for (int reg = 0; reg < 4; ++reg) {
        int grow = r0 + rt * 16 + lq * 4 + reg;
        if (grow < Mpts) {
          float v = acc2[j][rt][reg] + bias;
          cw[(size_t)grow * NCW + col] = f2bf(v);
          s[j] += v; ss[j] += v * v;
        }
      }
  }
#pragma unroll
  for (int j = 0; j < 4; ++j) {
    for (int off = 32; off > 0; off >>= 1) {
      s[j]  += __shfl_xor(s[j],  off);
      ss[j] += __shfl_xor(ss[j], off);
    }
  }
  float* st = stats + (blockIdx.x & 7) * 64;
  if (lane == 0) {
    for (int j = 0; j < NJ; ++j) {
      atomicAdd(&st[j0 + j], s[j]);
      atomicAdd(&st[32 + j0 + j], ss[j]);
    }
  }
}

// ================= K3: stats + geometry + wtab + gather-sum (2 pts/wave) =====
__global__ __launch_bounds__(256) void k3_out(
    const float* __restrict__ q_pts, const float* __restrict__ s_pts,
    const ushort* __restrict__ sfb, const int* __restrict__ nb,
    const float* __restrict__ kp, const float* __restrict__ gn_w,
    const float* __restrict__ gn_b, const ushort* __restrict__ cw,
    const float* __restrict__ stats, float* __restrict__ out)
{
  __shared__ float kpt[3][15];
  __shared__ float mus[16], rss[16];
  __shared__ float Atab[255], Btab[255];        // stride 17 per kernel point
  __shared__ float wtab[4][2][32][17];
  const int t = threadIdx.x;

  // fused k2: finalize GroupNorm stats from 8 replicas
  if (t < 15) {
    float S = 0.f, SS = 0.f;
#pragma unroll
    for (int r = 0; r < 8; ++r) { S += stats[r * 64 + t]; SS += stats[r * 64 + 32 + t]; }
    const float inv = 1.0f / (16.0f * (float)Mpts);
    float mu = S * inv;
    float var = SS * inv - mu * mu;
    mus[t] = mu;
    rss[t] = rsqrtf(var + 1e-5f);
  } else if (t < 60) {
    kpt[(t - 15) % 3][(t - 15) / 3] = kp[t - 15];
  }
  __syncthreads();
  if (t < 255) {       // fold GroupNorm affine at stride 17
    int k = t / 17, c = t % 17;
    if (c < 16) {
      int j = k * 16 + c;
      float a = rss[k] * gn_w[j];
      Atab[t] = a;
      Btab[t] = gn_b[j] - mus[k] * a;
    }
  }
  __syncthreads();

  const int wid = t >> 6, lane = t & 63;
  const int mbase = blockIdx.x * 8 + wid * 2;    // 2 points per wave

  // ---- geometry: ALL 64 lanes (lane>>5 = point, lane&31 = neighbor) ----
  int idx; int ksel = 0; float infl;
  {
    const int mg = mbase + (lane >> 5);
    const int hl = lane & 31;
    idx = nb[mg * Hn + hl];
    if (idx > Npts) idx = Npts;
    float qx = q_pts[mg * 3 + 0], qy = q_pts[mg * 3 + 1], qz = q_pts[mg * 3 + 2];
    float px, py, pz;
    if (idx < Npts) { px = s_pts[idx * 3 + 0]; py = s_pts[idx * 3 + 1]; pz = s_pts[idx * 3 + 2]; }
    else            { px = 1.0e6f; py = 1.0e6f; pz = 1.0e6f; }
    float nx = px - qx, ny = py - qy, nz = pz - qz;
    float best = 1e30f;
#pragma unroll
    for (int k = 0; k < Kk; ++k) {
      float dx = nx - kpt[0][k], dy = ny - kpt[1][k], dz = nz - kpt[2][k];
      float d = dx * dx + dy * dy + dz * dz;
      if (d < best) { best = d; ksel = k; }
    }
    infl = 1.f - sqrtf(best);
    infl = infl > 0.f ? infl : 0.f;
  }

  // ---- prefetch BOTH points' gathers (16 x 16B in flight) ----
  const int ch8 = lane & 15;
  const uint4* fb = (const uint4*)sfb;
  uint4 fv0[8], fv1[8];
#pragma unroll
  for (int j = 0; j < 8; ++j) {
    int h = (lane >> 4) + 4 * j;
    int ih0 = __shfl(idx, h);
    fv0[j] = fb[ih0 * 16 + ch8];
  }
#pragma unroll
  for (int j = 0; j < 8; ++j) {
    int h = (lane >> 4) + 4 * j;
    int ih1 = __shfl(idx, 32 + h);
    fv1[j] = fb[ih1 * 16 + ch8];
  }

  // ---- build both weight tables (wave-private -> no barrier) ----
#pragma unroll
  for (int p = 0; p < 2; ++p) {
    int h = lane >> 1;
    int kh = __shfl(ksel, p * 32 + h);
    float wI = __shfl(infl, p * 32 + h);
    int c0 = (lane & 1) * 8;
    uint4 cwv = *(const uint4*)(cw + (size_t)(mbase + p) * NCW + kh * 16 + c0);
    const uint* cu = (const uint*)&cwv;
#pragma unroll
    for (int i = 0; i < 4; ++i) {
      uint u = cu[i];
      int jj = kh * 17 + c0 + 2 * i;          // stride-17 A/B tables
      float v0 = __uint_as_float(u << 16);
      float v1 = __uint_as_float(u & 0xffff0000u);
      wtab[wid][p][h][c0 + 2 * i]     = fmaf(v0, Atab[jj],     Btab[jj])     * wI;
      wtab[wid][p][h][c0 + 2 * i + 1] = fmaf(v1, Atab[jj + 1], Btab[jj + 1]) * wI;
    }
  }

  // ---- main loops (one per point) ----
#define K3_MAIN(FV, P)                                                         \
  {                                                                            \
    f32x2 acc0 = {0.f, 0.f}, acc1 = {0.f, 0.f}, acc2 = {0.f, 0.f}, acc3 = {0.f, 0.f}; \
    _Pragma("unroll")                                                          \
    for (int j = 0; j < 8; ++j) {                                              \
      int h = (lane >> 4) + 4 * j;                                             \
      float w = wtab[wid][P][h][ch8];                                          \
      f32x2 w2 = {w, w};                                                       \
      uint ux = FV[j].x, uy = FV[j].y, uz = FV[j].z, uw = FV[j].w;             \
      f32x2 p0 = {__uint_as_float(ux << 16), __uint_as_float(ux & 0xffff0000u)}; \
      f32x2 p1 = {__uint_as_float(uy << 16), __uint_as_float(uy & 0xffff0000u)}; \
      f32x2 p2 = {__uint_as_float(uz << 16), __uint_as_float(uz & 0xffff0000u)}; \
      f32x2 p3 = {__uint_as_float(uw << 16), __uint_as_float(uw & 0xffff0000u)}; \
      acc0 = __builtin_elementwise_fma(p0, w2, acc0);                          \
      acc1 = __builtin_elementwise_fma(p1, w2, acc1);                          \
      acc2 = __builtin_elementwise_fma(p2, w2, acc2);                          \
      acc3 = __builtin_elementwise_fma(p3, w2, acc3);                          \
    }                                                                          \
    _Pragma("unroll")                                                          \
    for (int off = 16; off <= 32; off <<= 1) {                                 \
      acc0[0] += __shfl_xor(acc0[0], off); acc0[1] += __shfl_xor(acc0[1], off); \
      acc1[0] += __shfl_xor(acc1[0], off); acc1[1] += __shfl_xor(acc1[1], off); \
      acc2[0] += __shfl_xor(acc2[0], off); acc2[1] += __shfl_xor(acc2[1], off); \
      acc3[0] += __shfl_xor(acc3[0], off); acc3[1] += __shfl_xor(acc3[1], off); \
    }                                                                          \
    if (lane < 16) {                                                           \
      float4 o0; o0.x = acc0[0]; o0.y = acc0[1]; o0.z = acc1[0]; o0.w = acc1[1]; \
      float4 o1; o1.x = acc2[0]; o1.y = acc2[1]; o1.z = acc3[0]; o1.w = acc3[1]; \
      float* op = out + (size_t)(mbase + P) * Cc + ch8 * 8;                    \
      *(float4*)(op)     = o0;                                                 \
      *(float4*)(op + 4) = o1;                                                 \
    }                                                                          \
  }

  K3_MAIN(fv0, 0)
  K3_MAIN(fv1, 1)
#undef K3_MAIN
}

// ================= launcher ==================================================
extern "C" void kernel_launch(void* const* d_in, const int* in_sizes, int n_in,
                              void* d_out, int out_size, void* d_ws, size_t ws_size,
                              hipStream_t stream) {
  const float* q_pts  = (const float*)d_in[0];
  const float* s_pts  = (const float*)d_in[1];
  const float* sfeat  = (const float*)d_in[2];
  const int*   nb     = (const int*)d_in[3];
  const float* kp     = (const float*)d_in[4];
  const float* W1     = (const float*)d_in[5];
  const float* b1     = (const float*)d_in[6];
  const float* W2     = (const float*)d_in[7];
  const float* b2     = (const float*)d_in[8];
  const float* gn_w   = (const float*)d_in[9];
  const float* gn_b   = (const float*)d_in[10];
  float* out   = (float*)d_out;

  char* wsb = (char*)d_ws;
  float*  stats = (float*)wsb;
  ushort* sfb   = (ushort*)(wsb + 4096);
  ushort* W1t   = (ushort*)(wsb + 4096 + 12800256);
  ushort* W2t   = (ushort*)(wsb + 4096 + 12800256 + 32768);
  ushort* cwb   = (ushort*)(wsb + 4096 + 12800256 + 32768 + 61440);

  k0_weights<<<5, 256, 0, stream>>>(W1, W2, W1t, W2t, sfb, stats);
  k1_mlp<<<(Mpts + 63) / 64, 256, 0, stream>>>(sfeat, W1t, b1, W2t, b2, sfb, cwb, stats);
  k3_out<<<Mpts / 8, 256, 0, stream>>>(q_pts, s_pts, sfb, nb, kp, gn_w, gn_b, cwb, stats, out);
}

// Round 8
// 108.704 us; speedup vs baseline: 1.9882x; 1.9882x over previous
//
#include <hip/hip_runtime.h>
#include <hip/hip_bf16.h>

#define Mpts 50000
#define Npts 50000
#define Hn 32
#define Cc 128
#define Kk 15
#define NCW 240   // K*CPG = 15*16

typedef __attribute__((ext_vector_type(8))) short short8;
typedef __attribute__((ext_vector_type(4))) float f32x4;
typedef __attribute__((ext_vector_type(2))) float f32x2;

__device__ inline ushort f2bf(float f) {
  __hip_bfloat16 h = __float2bfloat16(f);
  return *reinterpret_cast<ushort*>(&h);
}

// ================= K0: transpose W1,W2 -> bf16 [n][k]; zero pad row & stats ==
__global__ __launch_bounds__(256) void k0_weights(
    const float* __restrict__ W1, const float* __restrict__ W2,
    ushort* __restrict__ W1t, ushort* __restrict__ W2t,
    ushort* __restrict__ sfb, float* __restrict__ stats)
{
  __shared__ ushort TT[240][66];
  const int t = threadIdx.x;
  const int b = blockIdx.x;
  if (b < 2) {                       // W1: 64 k-rows x 128 n-cols
    const int k0 = b * 64;
#pragma unroll
    for (int i = 0; i < 32; ++i) {
      int e = t + i * 256;           // coalesced
      int r = e >> 7, c = e & 127;
      TT[c][r] = f2bf(W1[(size_t)(k0 + r) * Cc + c]);
    }
    __syncthreads();
    int n = t >> 1, half = t & 1;
    union { short8 v[4]; ushort u[32]; } pk;
#pragma unroll
    for (int i = 0; i < 32; ++i) pk.u[i] = TT[n][half * 32 + i];
#pragma unroll
    for (int q = 0; q < 4; ++q)
      *(short8*)(W1t + (size_t)n * Cc + k0 + half * 32 + q * 8) = pk.v[q];
  } else if (b < 4) {                // W2: 64 k-rows x 240 n-cols
    const int k0 = (b - 2) * 64;
    for (int i = 0; i < 60; ++i) {
      int e = t + i * 256;           // coalesced
      int r = e / 240, c = e % 240;
      TT[c][r] = f2bf(W2[(size_t)(k0 + r) * NCW + c]);
    }
    __syncthreads();
    if (t < 240) {
      union { short8 v[8]; ushort u[64]; } pk;
#pragma unroll
      for (int i = 0; i < 64; ++i) pk.u[i] = TT[t][i];
#pragma unroll
      for (int q = 0; q < 8; ++q)
        *(short8*)(W2t + (size_t)t * Cc + k0 + q * 8) = pk.v[q];
    }
  } else {
    if (t < 16) {
      short8 z = short8{0,0,0,0,0,0,0,0};
      *(short8*)(sfb + (size_t)Npts * Cc + t * 8) = z;
    }
    if (t < 128) {
      float4 z4 = make_float4(0.f, 0.f, 0.f, 0.f);
      *(float4*)(stats + t * 4) = z4;
    }
  }
}

// ================= K1: fused MLP, BM=64 row-split, LDS-staged weights ========
__global__ __launch_bounds__(256, 3) void k1_mlp(
    const float* __restrict__ sfeat, const ushort* __restrict__ W1t,
    const float* __restrict__ b1, const ushort* __restrict__ W2t,
    const float* __restrict__ b2, ushort* __restrict__ sfb,
    ushort* __restrict__ cw, float* __restrict__ stats)
{
  __shared__ __align__(16) ushort shA[64 * 128];    // 16 KB: A tile -> h tile
  __shared__ __align__(16) ushort shW[128 * 128];   // 32 KB: W1t / W2t halves
  __shared__ float red[2][15][4];

  const int t = threadIdx.x;
  const int r0 = blockIdx.x * 64;
  const int wid = t >> 6, lane = t & 63;
  const int l16 = lane & 15, lq = lane >> 4;

  // ---- stage A (batch loads) + stage W1 into LDS ----
  float4 fA[4], fB[4];
#pragma unroll
  for (int p = 0; p < 4; ++p) {
    int id = p * 256 + t;
    int r = id >> 4, c = id & 15;
    int g = r0 + r;
    fA[p] = make_float4(0.f, 0.f, 0.f, 0.f);
    fB[p] = make_float4(0.f, 0.f, 0.f, 0.f);
    if (g < Mpts) {
      const float* src = sfeat + (size_t)g * Cc + c * 8;
      fA[p] = *(const float4*)(src);
      fB[p] = *(const float4*)(src + 4);
    }
  }
#pragma unroll
  for (int p = 0; p < 8; ++p) {      // W1t: 2048 16B-chunks
    int id = p * 256 + t;
    int r = id >> 4, c = id & 15;
    short8 v = *(const short8*)(W1t + r * Cc + c * 8);
    int byte = ((r * 256) + c * 16) ^ ((r & 7) << 4);
    *(short8*)((char*)shW + byte) = v;
  }
#pragma unroll
  for (int p = 0; p < 4; ++p) {
    int id = p * 256 + t;
    int r = id >> 4, c = id & 15;
    int g = r0 + r;
    union { short8 s; ushort u[8]; } pk;
    pk.u[0] = f2bf(fA[p].x); pk.u[1] = f2bf(fA[p].y); pk.u[2] = f2bf(fA[p].z); pk.u[3] = f2bf(fA[p].w);
    pk.u[4] = f2bf(fB[p].x); pk.u[5] = f2bf(fB[p].y); pk.u[6] = f2bf(fB[p].z); pk.u[7] = f2bf(fB[p].w);
    if (g < Mpts) *(short8*)(sfb + (size_t)g * Cc + c * 8) = pk.s;
    int byte = ((r * 256) + c * 16) ^ ((r & 7) << 4);
    *(short8*)((char*)shA + byte) = pk.s;
  }
  __syncthreads();

  const int arow = wid * 16 + l16;    // wave-private A/h rows
  const int axor = (arow & 7) << 4;

  // ---- stage 1: h[16 rows][128], B from LDS ----
  f32x4 acc1[8];
#pragma unroll
  for (int nt = 0; nt < 8; ++nt) acc1[nt] = f32x4{0.f, 0.f, 0.f, 0.f};
#pragma unroll
  for (int kt = 0; kt < 4; ++kt) {
    const int koff2 = (kt * 32 + lq * 8) * 2;
    short8 a = *(const short8*)((const char*)shA + ((arow * 256 + koff2) ^ axor));
#pragma unroll
    for (int nt = 0; nt < 8; ++nt) {
      int wrow = nt * 16 + l16;
      short8 b = *(const short8*)((const char*)shW + ((wrow * 256 + koff2) ^ ((wrow & 7) << 4)));
      acc1[nt] = __builtin_amdgcn_mfma_f32_16x16x32_bf16(a, b, acc1[nt], 0, 0, 0);
    }
  }
  // bias + LeakyReLU -> shA (own rows; no barrier needed)
#pragma unroll
  for (int nt = 0; nt < 8; ++nt) {
    int col = nt * 16 + l16;
    float bias = b1[col];
#pragma unroll
    for (int reg = 0; reg < 4; ++reg) {
      float h = acc1[nt][reg] + bias;
      h = h >= 0.f ? h : 0.1f * h;
      int row = wid * 16 + lq * 4 + reg;
      int byte = ((row * 256) + col * 2) ^ ((row & 7) << 4);
      *(ushort*)((char*)shA + byte) = f2bf(h);
    }
  }

  float s[15], ss[15];
#pragma unroll
  for (int j = 0; j < 15; ++j) { s[j] = 0.f; ss[j] = 0.f; }

  // ---- stage 2: two W2 LDS passes (j 0..7, then 8..14) ----
#pragma unroll
  for (int pass = 0; pass < 2; ++pass) {
    __syncthreads();                 // all waves done reading shW
    const int NR = pass ? 112 : 128; // rows staged this pass
    const int nch = NR * 16;
    for (int p = 0; p * 256 + t < nch; ++p) {
      int id = p * 256 + t;
      int r = id >> 4, c = id & 15;
      short8 v = *(const short8*)(W2t + (pass * 128 + r) * Cc + c * 8);
      int byte = ((r * 256) + c * 16) ^ ((r & 7) << 4);
      *(short8*)((char*)shW + byte) = v;
    }
    __syncthreads();                 // shW ready

    const int J0 = pass * 8, NJ = pass ? 7 : 8;
    f32x4 acc2[8];
#pragma unroll
    for (int j = 0; j < 8; ++j) acc2[j] = f32x4{0.f, 0.f, 0.f, 0.f};
#pragma unroll
    for (int kt = 0; kt < 4; ++kt) {
      const int koff2 = (kt * 32 + lq * 8) * 2;
      short8 a = *(const short8*)((const char*)shA + ((arow * 256 + koff2) ^ axor));
      for (int j = 0; j < NJ; ++j) {
        int wrow = j * 16 + l16;     // local row in this pass
        short8 b = *(const short8*)((const char*)shW + ((wrow * 256 + koff2) ^ ((wrow & 7) << 4)));
        acc2[j] = __builtin_amdgcn_mfma_f32_16x16x32_bf16(a, b, acc2[j], 0, 0, 0);
      }
    }
    for (int j = 0; j < NJ; ++j) {
      int col = (J0 + j) * 16 + l16;
      float bias = b2[col];
#pragma unroll
      for (int reg = 0; reg < 4; ++reg) {
        int grow = r0 + wid * 16 + lq * 4 + reg;
        if (grow < Mpts) {
          float v = acc2[j][reg] + bias;
          cw[(size_t)grow * NCW + col] = f2bf(v);
          s[J0 + j] += v; ss[J0 + j] += v * v;
        }
      }
    }
  }

  // ---- stats: wave shfl-reduce -> block reduce -> replicated atomics ----
#pragma unroll
  for (int j = 0; j < 15; ++j) {
    for (int off = 32; off > 0; off >>= 1) {
      s[j]  += __shfl_xor(s[j],  off);
      ss[j] += __shfl_xor(ss[j], off);
    }
  }
  if (lane == 0) {
#pragma unroll
    for (int j = 0; j < 15; ++j) { red[0][j][wid] = s[j]; red[1][j][wid] = ss[j]; }
  }
  __syncthreads();
  float* st = stats + (blockIdx.x & 7) * 64;
  if (t < 15) {
    float S = red[0][t][0] + red[0][t][1] + red[0][t][2] + red[0][t][3];
    atomicAdd(&st[t], S);
  } else if (t >= 32 && t < 47) {
    int j = t - 32;
    float SS = red[1][j][0] + red[1][j][1] + red[1][j][2] + red[1][j][3];
    atomicAdd(&st[32 + j], SS);
  }
}

// ================= K3: stats + geometry + wtab + gather-sum (2 pts/wave) =====
__global__ __launch_bounds__(256) void k3_out(
    const float* __restrict__ q_pts, const float* __restrict__ s_pts,
    const ushort* __restrict__ sfb, const int* __restrict__ nb,
    const float* __restrict__ kp, const float* __restrict__ gn_w,
    const float* __restrict__ gn_b, const ushort* __restrict__ cw,
    const float* __restrict__ stats, float* __restrict__ out)
{
  __shared__ float kpt[3][15];
  __shared__ float mus[16], rss[16];
  __shared__ float Atab[255], Btab[255];        // stride 17 per kernel point
  __shared__ float wtab[4][2][32][17];
  const int t = threadIdx.x;

  // fused k2: finalize GroupNorm stats from 8 replicas
  if (t < 15) {
    float S = 0.f, SS = 0.f;
#pragma unroll
    for (int r = 0; r < 8; ++r) { S += stats[r * 64 + t]; SS += stats[r * 64 + 32 + t]; }
    const float inv = 1.0f / (16.0f * (float)Mpts);
    float mu = S * inv;
    float var = SS * inv - mu * mu;
    mus[t] = mu;
    rss[t] = rsqrtf(var + 1e-5f);
  } else if (t < 60) {
    kpt[(t - 15) % 3][(t - 15) / 3] = kp[t - 15];
  }
  __syncthreads();
  if (t < 255) {       // fold GroupNorm affine at stride 17
    int k = t / 17, c = t % 17;
    if (c < 16) {
      int j = k * 16 + c;
      float a = rss[k] * gn_w[j];
      Atab[t] = a;
      Btab[t] = gn_b[j] - mus[k] * a;
    }
  }
  __syncthreads();

  const int wid = t >> 6, lane = t & 63;
  const int mbase = blockIdx.x * 8 + wid * 2;    // 2 points per wave

  // ---- geometry: ALL 64 lanes (lane>>5 = point, lane&31 = neighbor) ----
  int idx; int ksel = 0; float infl;
  {
    const int mg = mbase + (lane >> 5);
    const int hl = lane & 31;
    idx = nb[mg * Hn + hl];
    if (idx > Npts) idx = Npts;
    float qx = q_pts[mg * 3 + 0], qy = q_pts[mg * 3 + 1], qz = q_pts[mg * 3 + 2];
    float px, py, pz;
    if (idx < Npts) { px = s_pts[idx * 3 + 0]; py = s_pts[idx * 3 + 1]; pz = s_pts[idx * 3 + 2]; }
    else            { px = 1.0e6f; py = 1.0e6f; pz = 1.0e6f; }
    float nx = px - qx, ny = py - qy, nz = pz - qz;
    float best = 1e30f;
#pragma unroll
    for (int k = 0; k < Kk; ++k) {
      float dx = nx - kpt[0][k], dy = ny - kpt[1][k], dz = nz - kpt[2][k];
      float d = dx * dx + dy * dy + dz * dz;
      if (d < best) { best = d; ksel = k; }
    }
    infl = 1.f - sqrtf(best);
    infl = infl > 0.f ? infl : 0.f;
  }

  // ---- prefetch BOTH points' gathers (16 x 16B in flight) ----
  const int ch8 = lane & 15;
  const uint4* fb = (const uint4*)sfb;
  uint4 fv0[8], fv1[8];
#pragma unroll
  for (int j = 0; j < 8; ++j) {
    int h = (lane >> 4) + 4 * j;
    int ih0 = __shfl(idx, h);
    fv0[j] = fb[ih0 * 16 + ch8];
  }
#pragma unroll
  for (int j = 0; j < 8; ++j) {
    int h = (lane >> 4) + 4 * j;
    int ih1 = __shfl(idx, 32 + h);
    fv1[j] = fb[ih1 * 16 + ch8];
  }

  // ---- build both weight tables (wave-private -> no barrier) ----
#pragma unroll
  for (int p = 0; p < 2; ++p) {
    int h = lane >> 1;
    int kh = __shfl(ksel, p * 32 + h);
    float wI = __shfl(infl, p * 32 + h);
    int c0 = (lane & 1) * 8;
    uint4 cwv = *(const uint4*)(cw + (size_t)(mbase + p) * NCW + kh * 16 + c0);
    const uint* cu = (const uint*)&cwv;
#pragma unroll
    for (int i = 0; i < 4; ++i) {
      uint u = cu[i];
      int jj = kh * 17 + c0 + 2 * i;          // stride-17 A/B tables
      float v0 = __uint_as_float(u << 16);
      float v1 = __uint_as_float(u & 0xffff0000u);
      wtab[wid][p][h][c0 + 2 * i]     = fmaf(v0, Atab[jj],     Btab[jj])     * wI;
      wtab[wid][p][h][c0 + 2 * i + 1] = fmaf(v1, Atab[jj + 1], Btab[jj + 1]) * wI;
    }
  }

  // ---- main loops (one per point) ----
#define K3_MAIN(FV, P)                                                         \
  {                                                                            \
    f32x2 acc0 = {0.f, 0.f}, acc1 = {0.f, 0.f}, acc2 = {0.f, 0.f}, acc3 = {0.f, 0.f}; \
    _Pragma("unroll")                                                          \
    for (int j = 0; j < 8; ++j) {                                              \
      int h = (lane >> 4) + 4 * j;                                             \
      float w = wtab[wid][P][h][ch8];                                          \
      f32x2 w2 = {w, w};                                                       \
      uint ux = FV[j].x, uy = FV[j].y, uz = FV[j].z, uw = FV[j].w;             \
      f32x2 p0 = {__uint_as_float(ux << 16), __uint_as_float(ux & 0xffff0000u)}; \
      f32x2 p1 = {__uint_as_float(uy << 16), __uint_as_float(uy & 0xffff0000u)}; \
      f32x2 p2 = {__uint_as_float(uz << 16), __uint_as_float(uz & 0xffff0000u)}; \
      f32x2 p3 = {__uint_as_float(uw << 16), __uint_as_float(uw & 0xffff0000u)}; \
      acc0 = __builtin_elementwise_fma(p0, w2, acc0);                          \
      acc1 = __builtin_elementwise_fma(p1, w2, acc1);                          \
      acc2 = __builtin_elementwise_fma(p2, w2, acc2);                          \
      acc3 = __builtin_elementwise_fma(p3, w2, acc3);                          \
    }                                                                          \
    _Pragma("unroll")                                                          \
    for (int off = 16; off <= 32; off <<= 1) {                                 \
      acc0[0] += __shfl_xor(acc0[0], off); acc0[1] += __shfl_xor(acc0[1], off); \
      acc1[0] += __shfl_xor(acc1[0], off); acc1[1] += __shfl_xor(acc1[1], off); \
      acc2[0] += __shfl_xor(acc2[0], off); acc2[1] += __shfl_xor(acc2[1], off); \
      acc3[0] += __shfl_xor(acc3[0], off); acc3[1] += __shfl_xor(acc3[1], off); \
    }                                                                          \
    if (lane < 16) {                                                           \
      float4 o0; o0.x = acc0[0]; o0.y = acc0[1]; o0.z = acc1[0]; o0.w = acc1[1]; \
      float4 o1; o1.x = acc2[0]; o1.y = acc2[1]; o1.z = acc3[0]; o1.w = acc3[1]; \
      float* op = out + (size_t)(mbase + P) * Cc + ch8 * 8;                    \
      *(float4*)(op)     = o0;                                                 \
      *(float4*)(op + 4) = o1;                                                 \
    }                                                                          \
  }

  K3_MAIN(fv0, 0)
  K3_MAIN(fv1, 1)
#undef K3_MAIN
}

// ================= launcher ==================================================
extern "C" void kernel_launch(void* const* d_in, const int* in_sizes, int n_in,
                              void* d_out, int out_size, void* d_ws, size_t ws_size,
                              hipStream_t stream) {
  const float* q_pts  = (const float*)d_in[0];
  const float* s_pts  = (const float*)d_in[1];
  const float* sfeat  = (const float*)d_in[2];
  const int*   nb     = (const int*)d_in[3];
  const float* kp     = (const float*)d_in[4];
  const float* W1     = (const float*)d_in[5];
  const float* b1     = (const float*)d_in[6];
  const float* W2     = (const float*)d_in[7];
  const float* b2     = (const float*)d_in[8];
  const float* gn_w   = (const float*)d_in[9];
  const float* gn_b   = (const float*)d_in[10];
  float* out   = (float*)d_out;

  char* wsb = (char*)d_ws;
  float*  stats = (float*)wsb;
  ushort* sfb   = (ushort*)(wsb + 4096);
  ushort* W1t   = (ushort*)(wsb + 4096 + 12800256);
  ushort* W2t   = (ushort*)(wsb + 4096 + 12800256 + 32768);
  ushort* cwb   = (ushort*)(wsb + 4096 + 12800256 + 32768 + 61440);

  k0_weights<<<5, 256, 0, stream>>>(W1, W2, W1t, W2t, sfb, stats);
  k1_mlp<<<(Mpts + 63) / 64, 256, 0, stream>>>(sfeat, W1t, b1, W2t, b2, sfb, cwb, stats);
  k3_out<<<Mpts / 8, 256, 0, stream>>>(q_pts, s_pts, sfb, nb, kp, gn_w, gn_b, cwb, stats, out);
}

// Round 9
// 108.046 us; speedup vs baseline: 2.0003x; 1.0061x over previous
//
#include <hip/hip_runtime.h>
#include <hip/hip_bf16.h>

#define Mpts 50000
#define Npts 50000
#define Hn 32
#define Cc 128
#define Kk 15
#define NCW 240   // K*CPG = 15*16

typedef __attribute__((ext_vector_type(8))) short short8;
typedef __attribute__((ext_vector_type(4))) float f32x4;
typedef __attribute__((ext_vector_type(2))) float f32x2;

__device__ inline ushort f2bf(float f) {
  __hip_bfloat16 h = __float2bfloat16(f);
  return *reinterpret_cast<ushort*>(&h);
}

#define PIN4(v) asm volatile("" : "+v"((v).x), "+v"((v).y), "+v"((v).z), "+v"((v).w))

// ================= K0: transpose W1,W2 -> bf16 [n][k]; zero pad row & stats ==
__global__ __launch_bounds__(256) void k0_weights(
    const float* __restrict__ W1, const float* __restrict__ W2,
    ushort* __restrict__ W1t, ushort* __restrict__ W2t,
    ushort* __restrict__ sfb, float* __restrict__ stats)
{
  __shared__ ushort TT[240][66];
  const int t = threadIdx.x;
  const int b = blockIdx.x;
  if (b < 2) {                       // W1: 64 k-rows x 128 n-cols
    const int k0 = b * 64;
#pragma unroll
    for (int i = 0; i < 32; ++i) {
      int e = t + i * 256;           // coalesced
      int r = e >> 7, c = e & 127;
      TT[c][r] = f2bf(W1[(size_t)(k0 + r) * Cc + c]);
    }
    __syncthreads();
    int n = t >> 1, half = t & 1;
    union { short8 v[4]; ushort u[32]; } pk;
#pragma unroll
    for (int i = 0; i < 32; ++i) pk.u[i] = TT[n][half * 32 + i];
#pragma unroll
    for (int q = 0; q < 4; ++q)
      *(short8*)(W1t + (size_t)n * Cc + k0 + half * 32 + q * 8) = pk.v[q];
  } else if (b < 4) {                // W2: 64 k-rows x 240 n-cols
    const int k0 = (b - 2) * 64;
    for (int i = 0; i < 60; ++i) {
      int e = t + i * 256;           // coalesced
      int r = e / 240, c = e % 240;
      TT[c][r] = f2bf(W2[(size_t)(k0 + r) * NCW + c]);
    }
    __syncthreads();
    if (t < 240) {
      union { short8 v[8]; ushort u[64]; } pk;
#pragma unroll
      for (int i = 0; i < 64; ++i) pk.u[i] = TT[t][i];
#pragma unroll
      for (int q = 0; q < 8; ++q)
        *(short8*)(W2t + (size_t)t * Cc + k0 + q * 8) = pk.v[q];
    }
  } else {
    if (t < 16) {
      short8 z = short8{0,0,0,0,0,0,0,0};
      *(short8*)(sfb + (size_t)Npts * Cc + t * 8) = z;
    }
    if (t < 128) {
      float4 z4 = make_float4(0.f, 0.f, 0.f, 0.f);
      *(float4*)(stats + t * 4) = z4;
    }
  }
}

// ================= K1: fused MLP, BM=64 row-split, LDS weights, pinned loads =
__global__ __launch_bounds__(256, 3) void k1_mlp(
    const float* __restrict__ sfeat, const ushort* __restrict__ W1t,
    const float* __restrict__ b1, const ushort* __restrict__ W2t,
    const float* __restrict__ b2, ushort* __restrict__ sfb,
    ushort* __restrict__ cw, float* __restrict__ stats)
{
  __shared__ __align__(16) ushort shA[64 * 128];    // 16 KB: A tile -> h tile
  __shared__ __align__(16) ushort shW[128 * 128];   // 32 KB: W1t / W2t halves
  __shared__ float red[2][15][4];

  const int t = threadIdx.x;
  const int r0 = blockIdx.x * 64;
  const int wid = t >> 6, lane = t & 63;
  const int l16 = lane & 15, lq = lane >> 4;

  // ---- issue sfeat loads (HBM) first ----
  float4 fA[4], fB[4];
#pragma unroll
  for (int p = 0; p < 4; ++p) {
    int id = p * 256 + t;
    int r = id >> 4, c = id & 15;
    int g = r0 + r;
    fA[p] = make_float4(0.f, 0.f, 0.f, 0.f);
    fB[p] = make_float4(0.f, 0.f, 0.f, 0.f);
    if (g < Mpts) {
      const float* src = sfeat + (size_t)g * Cc + c * 8;
      fA[p] = *(const float4*)(src);
      fB[p] = *(const float4*)(src + 4);
    }
  }
  // ---- issue W1 loads (L2) ----
  uint4 wv[8];
#pragma unroll
  for (int p = 0; p < 8; ++p) {
    int id = p * 256 + t;
    int r = id >> 4, c = id & 15;
    wv[p] = *(const uint4*)(W1t + r * Cc + c * 8);
  }
#pragma unroll
  for (int p = 0; p < 8; ++p) PIN4(wv[p]);
  // ---- store W1 to LDS (sfeat still in flight) ----
#pragma unroll
  for (int p = 0; p < 8; ++p) {
    int id = p * 256 + t;
    int r = id >> 4, c = id & 15;
    int byte = ((r * 256) + c * 16) ^ ((r & 7) << 4);
    *(uint4*)((char*)shW + byte) = wv[p];
  }
#pragma unroll
  for (int p = 0; p < 4; ++p) { PIN4(fA[p]); PIN4(fB[p]); }
  // ---- convert + store A to LDS + global sfb ----
#pragma unroll
  for (int p = 0; p < 4; ++p) {
    int id = p * 256 + t;
    int r = id >> 4, c = id & 15;
    int g = r0 + r;
    union { short8 s; ushort u[8]; } pk;
    pk.u[0] = f2bf(fA[p].x); pk.u[1] = f2bf(fA[p].y); pk.u[2] = f2bf(fA[p].z); pk.u[3] = f2bf(fA[p].w);
    pk.u[4] = f2bf(fB[p].x); pk.u[5] = f2bf(fB[p].y); pk.u[6] = f2bf(fB[p].z); pk.u[7] = f2bf(fB[p].w);
    if (g < Mpts) *(short8*)(sfb + (size_t)g * Cc + c * 8) = pk.s;
    int byte = ((r * 256) + c * 16) ^ ((r & 7) << 4);
    *(short8*)((char*)shA + byte) = pk.s;
  }
  __syncthreads();

  const int arow = wid * 16 + l16;    // wave-private A/h rows
  const int axor = (arow & 7) << 4;

  // ---- stage 1: h[16 rows][128], B from LDS ----
  f32x4 acc1[8];
#pragma unroll
  for (int nt = 0; nt < 8; ++nt) acc1[nt] = f32x4{0.f, 0.f, 0.f, 0.f};
#pragma unroll
  for (int kt = 0; kt < 4; ++kt) {
    const int koff2 = (kt * 32 + lq * 8) * 2;
    short8 a = *(const short8*)((const char*)shA + ((arow * 256 + koff2) ^ axor));
#pragma unroll
    for (int nt = 0; nt < 8; ++nt) {
      int wrow = nt * 16 + l16;
      short8 b = *(const short8*)((const char*)shW + ((wrow * 256 + koff2) ^ ((wrow & 7) << 4)));
      acc1[nt] = __builtin_amdgcn_mfma_f32_16x16x32_bf16(a, b, acc1[nt], 0, 0, 0);
    }
  }
  // bias + LeakyReLU -> shA (own rows; no barrier needed)
#pragma unroll
  for (int nt = 0; nt < 8; ++nt) {
    int col = nt * 16 + l16;
    float bias = b1[col];
#pragma unroll
    for (int reg = 0; reg < 4; ++reg) {
      float h = acc1[nt][reg] + bias;
      h = h >= 0.f ? h : 0.1f * h;
      int row = wid * 16 + lq * 4 + reg;
      int byte = ((row * 256) + col * 2) ^ ((row & 7) << 4);
      *(ushort*)((char*)shA + byte) = f2bf(h);
    }
  }

  float s[15], ss[15];
#pragma unroll
  for (int j = 0; j < 15; ++j) { s[j] = 0.f; ss[j] = 0.f; }

  // ---- stage 2: two W2 LDS passes (j 0..7, then 8..14), pinned staging ----
#pragma unroll
  for (int pass = 0; pass < 2; ++pass) {
    __syncthreads();                 // all waves done reading shW
    const int NCH = pass ? 7 : 8;    // chunks per thread (128 / 112 rows)
    uint4 wv2[8];
#pragma unroll
    for (int p = 0; p < NCH; ++p) {
      int id = p * 256 + t;
      int r = id >> 4, c = id & 15;
      wv2[p] = *(const uint4*)(W2t + (size_t)(pass * 128 + r) * Cc + c * 8);
    }
#pragma unroll
    for (int p = 0; p < NCH; ++p) PIN4(wv2[p]);
#pragma unroll
    for (int p = 0; p < NCH; ++p) {
      int id = p * 256 + t;
      int r = id >> 4, c = id & 15;
      int byte = ((r * 256) + c * 16) ^ ((r & 7) << 4);
      *(uint4*)((char*)shW + byte) = wv2[p];
    }
    __syncthreads();                 // shW ready

    const int J0 = pass * 8, NJ = pass ? 7 : 8;
    f32x4 acc2[8];
#pragma unroll
    for (int j = 0; j < 8; ++j) acc2[j] = f32x4{0.f, 0.f, 0.f, 0.f};
#pragma unroll
    for (int kt = 0; kt < 4; ++kt) {
      const int koff2 = (kt * 32 + lq * 8) * 2;
      short8 a = *(const short8*)((const char*)shA + ((arow * 256 + koff2) ^ axor));
      for (int j = 0; j < NJ; ++j) {
        int wrow = j * 16 + l16;     // local row in this pass
        short8 b = *(const short8*)((const char*)shW + ((wrow * 256 + koff2) ^ ((wrow & 7) << 4)));
        acc2[j] = __builtin_amdgcn_mfma_f32_16x16x32_bf16(a, b, acc2[j], 0, 0, 0);
      }
    }
    for (int j = 0; j < NJ; ++j) {
      int col = (J0 + j) * 16 + l16;
      float bias = b2[col];
#pragma unroll
      for (int reg = 0; reg < 4; ++reg) {
        int grow = r0 + wid * 16 + lq * 4 + reg;
        if (grow < Mpts) {
          float v = acc2[j][reg] + bias;
          cw[(size_t)grow * NCW + col] = f2bf(v);
          s[J0 + j] += v; ss[J0 + j] += v * v;
        }
      }
    }
  }

  // ---- stats: wave shfl-reduce -> block reduce -> replicated atomics ----
#pragma unroll
  for (int j = 0; j < 15; ++j) {
    for (int off = 32; off > 0; off >>= 1) {
      s[j]  += __shfl_xor(s[j],  off);
      ss[j] += __shfl_xor(ss[j], off);
    }
  }
  if (lane == 0) {
#pragma unroll
    for (int j = 0; j < 15; ++j) { red[0][j][wid] = s[j]; red[1][j][wid] = ss[j]; }
  }
  __syncthreads();
  float* st = stats + (blockIdx.x & 7) * 64;
  if (t < 15) {
    float S = red[0][t][0] + red[0][t][1] + red[0][t][2] + red[0][t][3];
    atomicAdd(&st[t], S);
  } else if (t >= 32 && t < 47) {
    int j = t - 32;
    float SS = red[1][j][0] + red[1][j][1] + red[1][j][2] + red[1][j][3];
    atomicAdd(&st[32 + j], SS);
  }
}

// ================= K3: stats + geometry + wtab + gather-sum (2 pts/wave) =====
__global__ __launch_bounds__(256, 4) void k3_out(
    const float* __restrict__ q_pts, const float* __restrict__ s_pts,
    const ushort* __restrict__ sfb, const int* __restrict__ nb,
    const float* __restrict__ kp, const float* __restrict__ gn_w,
    const float* __restrict__ gn_b, const ushort* __restrict__ cw,
    const float* __restrict__ stats, float* __restrict__ out)
{
  __shared__ float kpt[3][15];
  __shared__ float mus[16], rss[16];
  __shared__ float Atab[255], Btab[255];        // stride 17 per kernel point
  __shared__ float wtab[4][2][32][17];
  const int t = threadIdx.x;

  // fused k2: finalize GroupNorm stats from 8 replicas
  if (t < 15) {
    float S = 0.f, SS = 0.f;
#pragma unroll
    for (int r = 0; r < 8; ++r) { S += stats[r * 64 + t]; SS += stats[r * 64 + 32 + t]; }
    const float inv = 1.0f / (16.0f * (float)Mpts);
    float mu = S * inv;
    float var = SS * inv - mu * mu;
    mus[t] = mu;
    rss[t] = rsqrtf(var + 1e-5f);
  } else if (t < 60) {
    kpt[(t - 15) % 3][(t - 15) / 3] = kp[t - 15];
  }
  __syncthreads();
  if (t < 255) {       // fold GroupNorm affine at stride 17
    int k = t / 17, c = t % 17;
    if (c < 16) {
      int j = k * 16 + c;
      float a = rss[k] * gn_w[j];
      Atab[t] = a;
      Btab[t] = gn_b[j] - mus[k] * a;
    }
  }
  __syncthreads();

  const int wid = t >> 6, lane = t & 63;
  const int mbase = blockIdx.x * 8 + wid * 2;    // 2 points per wave

  // ---- geometry: ALL 64 lanes (lane>>5 = point, lane&31 = neighbor) ----
  int idx; int ksel = 0; float infl;
  {
    const int mg = mbase + (lane >> 5);
    const int hl = lane & 31;
    idx = nb[mg * Hn + hl];
    if (idx > Npts) idx = Npts;
    float qx = q_pts[mg * 3 + 0], qy = q_pts[mg * 3 + 1], qz = q_pts[mg * 3 + 2];
    float px, py, pz;
    if (idx < Npts) { px = s_pts[idx * 3 + 0]; py = s_pts[idx * 3 + 1]; pz = s_pts[idx * 3 + 2]; }
    else            { px = 1.0e6f; py = 1.0e6f; pz = 1.0e6f; }
    float nx = px - qx, ny = py - qy, nz = pz - qz;
    float best = 1e30f;
#pragma unroll
    for (int k = 0; k < Kk; ++k) {
      float dx = nx - kpt[0][k], dy = ny - kpt[1][k], dz = nz - kpt[2][k];
      float d = dx * dx + dy * dy + dz * dz;
      if (d < best) { best = d; ksel = k; }
    }
    infl = 1.f - sqrtf(best);
    infl = infl > 0.f ? infl : 0.f;
  }

  // ---- issue BOTH points' gathers (16 x 16B in flight) ----
  const int ch8 = lane & 15;
  const uint4* fb = (const uint4*)sfb;
  uint4 fv0[8], fv1[8];
#pragma unroll
  for (int j = 0; j < 8; ++j) {
    int h = (lane >> 4) + 4 * j;
    int ih0 = __shfl(idx, h);
    fv0[j] = fb[ih0 * 16 + ch8];
  }
#pragma unroll
  for (int j = 0; j < 8; ++j) {
    int h = (lane >> 4) + 4 * j;
    int ih1 = __shfl(idx, 32 + h);
    fv1[j] = fb[ih1 * 16 + ch8];
  }

  // ---- build both weight tables while gathers fly (wave-private) ----
#pragma unroll
  for (int p = 0; p < 2; ++p) {
    int h = lane >> 1;
    int kh = __shfl(ksel, p * 32 + h);
    float wI = __shfl(infl, p * 32 + h);
    int c0 = (lane & 1) * 8;
    uint4 cwv = *(const uint4*)(cw + (size_t)(mbase + p) * NCW + kh * 16 + c0);
    const uint* cu = (const uint*)&cwv;
#pragma unroll
    for (int i = 0; i < 4; ++i) {
      uint u = cu[i];
      int jj = kh * 17 + c0 + 2 * i;          // stride-17 A/B tables
      float v0 = __uint_as_float(u << 16);
      float v1 = __uint_as_float(u & 0xffff0000u);
      wtab[wid][p][h][c0 + 2 * i]     = fmaf(v0, Atab[jj],     Btab[jj])     * wI;
      wtab[wid][p][h][c0 + 2 * i + 1] = fmaf(v1, Atab[jj + 1], Btab[jj + 1]) * wI;
    }
  }

  // ---- pin gathers: force all 16 loads resident before the FMA loops ----
#pragma unroll
  for (int j = 0; j < 8; ++j) { PIN4(fv0[j]); PIN4(fv1[j]); }

  // ---- main loops (one per point) ----
#define K3_MAIN(FV, P)                                                         \
  {                                                                            \
    f32x2 acc0 = {0.f, 0.f}, acc1 = {0.f, 0.f}, acc2 = {0.f, 0.f}, acc3 = {0.f, 0.f}; \
    _Pragma("unroll")                                                          \
    for (int j = 0; j < 8; ++j) {                                              \
      int h = (lane >> 4) + 4 * j;                                             \
      float w = wtab[wid][P][h][ch8];                                          \
      f32x2 w2 = {w, w};                                                       \
      uint ux = FV[j].x, uy = FV[j].y, uz = FV[j].z, uw = FV[j].w;             \
      f32x2 p0 = {__uint_as_float(ux << 16), __uint_as_float(ux & 0xffff0000u)}; \
      f32x2 p1 = {__uint_as_float(uy << 16), __uint_as_float(uy & 0xffff0000u)}; \
      f32x2 p2 = {__uint_as_float(uz << 16), __uint_as_float(uz & 0xffff0000u)}; \
      f32x2 p3 = {__uint_as_float(uw << 16), __uint_as_float(uw & 0xffff0000u)}; \
      acc0 = __builtin_elementwise_fma(p0, w2, acc0);                          \
      acc1 = __builtin_elementwise_fma(p1, w2, acc1);                          \
      acc2 = __builtin_elementwise_fma(p2, w2, acc2);                          \
      acc3 = __builtin_elementwise_fma(p3, w2, acc3);                          \
    }                                                                          \
    _Pragma("unroll")                                                          \
    for (int off = 16; off <= 32; off <<= 1) {                                 \
      acc0[0] += __shfl_xor(acc0[0], off); acc0[1] += __shfl_xor(acc0[1], off); \
      acc1[0] += __shfl_xor(acc1[0], off); acc1[1] += __shfl_xor(acc1[1], off); \
      acc2[0] += __shfl_xor(acc2[0], off); acc2[1] += __shfl_xor(acc2[1], off); \
      acc3[0] += __shfl_xor(acc3[0], off); acc3[1] += __shfl_xor(acc3[1], off); \
    }                                                                          \
    if (lane < 16) {                                                           \
      float4 o0; o0.x = acc0[0]; o0.y = acc0[1]; o0.z = acc1[0]; o0.w = acc1[1]; \
      float4 o1; o1.x = acc2[0]; o1.y = acc2[1]; o1.z = acc3[0]; o1.w = acc3[1]; \
      float* op = out + (size_t)(mbase + P) * Cc + ch8 * 8;                    \
      *(float4*)(op)     = o0;                                                 \
      *(float4*)(op + 4) = o1;                                                 \
    }                                                                          \
  }

  K3_MAIN(fv0, 0)
  K3_MAIN(fv1, 1)
#undef K3_MAIN
}

// ================= launcher ==================================================
extern "C" void kernel_launch(void* const* d_in, const int* in_sizes, int n_in,
                              void* d_out, int out_size, void* d_ws, size_t ws_size,
                              hipStream_t stream) {
  const float* q_pts  = (const float*)d_in[0];
  const float* s_pts  = (const float*)d_in[1];
  const float* sfeat  = (const float*)d_in[2];
  const int*   nb     = (const int*)d_in[3];
  const float* kp     = (const float*)d_in[4];
  const float* W1     = (const float*)d_in[5];
  const float* b1     = (const float*)d_in[6];
  const float* W2     = (const float*)d_in[7];
  const float* b2     = (const float*)d_in[8];
  const float* gn_w   = (const float*)d_in[9];
  const float* gn_b   = (const float*)d_in[10];
  float* out   = (float*)d_out;

  char* wsb = (char*)d_ws;
  float*  stats = (float*)wsb;
  ushort* sfb   = (ushort*)(wsb + 4096);
  ushort* W1t   = (ushort*)(wsb + 4096 + 12800256);
  ushort* W2t   = (ushort*)(wsb + 4096 + 12800256 + 32768);
  ushort* cwb   = (ushort*)(wsb + 4096 + 12800256 + 32768 + 61440);

  k0_weights<<<5, 256, 0, stream>>>(W1, W2, W1t, W2t, sfb, stats);
  k1_mlp<<<(Mpts + 63) / 64, 256, 0, stream>>>(sfeat, W1t, b1, W2t, b2, sfb, cwb, stats);
  k3_out<<<Mpts / 8, 256, 0, stream>>>(q_pts, s_pts, sfb, nb, kp, gn_w, gn_b, cwb, stats, out);
}